// Round 2
// baseline (12876.466 us; speedup 1.0000x reference)
//
#include <hip/hip_runtime.h>

typedef unsigned short ushort_t;
typedef __attribute__((ext_vector_type(8))) short short8;
typedef __attribute__((ext_vector_type(4))) float f32x4;
typedef __attribute__((ext_vector_type(4))) int i32x4;

#define NB   256     // batch
#define NT   512     // timesteps
#define ND   512     // input dim
#define NH   1024    // hidden dim
#define KK   1536    // NH + ND (concatenated K)
#define BK   128     // K-chunk staged in LDS per iteration

__device__ __forceinline__ ushort_t f2bf(float f) {
  union { float f; unsigned u; } v; v.f = f;
  unsigned u = v.u;
  return (ushort_t)((u + 0x7FFFu + ((u >> 16) & 1u)) >> 16);
}
__device__ __forceinline__ int pack2(float a, float b) {
  return (int)(((unsigned)f2bf(b) << 16) | (unsigned)f2bf(a));
}
__device__ __forceinline__ float sigmoidf_(float x) {
  return 1.f / (1.f + __expf(-x));
}
__device__ __forceinline__ float tanhf_(float x) {
  return 1.f - 2.f / (__expf(2.f * x) + 1.f);  // safe: overflow -> 1, underflow -> -1
}

// ---------------------------------------------------------------------------
// Repack weights into bf16, N-major (k-contiguous):
//   B1t [2048][1536]: cols 0..1023 = z-gate ([U_z;W_z]), 1024..2047 = r-gate.
//   B2t [1024][1536]: candidate ([U;W]).
// ---------------------------------------------------------------------------
__global__ void repack_weights(const float* __restrict__ U,  const float* __restrict__ W,
                               const float* __restrict__ Uz, const float* __restrict__ Wz,
                               const float* __restrict__ Ur, const float* __restrict__ Wr,
                               ushort_t* __restrict__ B1t, ushort_t* __restrict__ B2t) {
  const int kt = blockIdx.x, nt = blockIdx.y, which = blockIdx.z;
  if (which == 1 && nt >= 16) return;       // B2t has only 1024 cols
  __shared__ float tile[64][65];            // +1 pad: conflict-free transpose
  const int k0 = kt * 64, n0 = nt * 64;
  const int tid = threadIdx.x;
  for (int i = 0; i < 16; ++i) {
    int e = tid + i * 256;
    int r = e >> 6, c = e & 63;             // r = k-local, c = n-local
    int k = k0 + r, n = n0 + c;
    int nn = n & 1023;
    const float* src;
    if (which == 0) {
      if (k < NH) src = (n < NH ? Uz : Ur) + (size_t)k * NH + nn;
      else        src = (n < NH ? Wz : Wr) + (size_t)(k - NH) * NH + nn;
    } else {
      if (k < NH) src = U + (size_t)k * NH + nn;
      else        src = W + (size_t)(k - NH) * NH + nn;
    }
    tile[r][c] = *src;
  }
  __syncthreads();
  ushort_t* dst = (which == 0) ? B1t : B2t;
  for (int i = 0; i < 2; ++i) {
    int cch = tid + i * 256;                // 512 chunks: 64 n-rows x 8 k-chunks
    int nl = cch >> 3, kc = (cch & 7) * 8;
    ushort_t tmp[8];
#pragma unroll
    for (int j = 0; j < 8; ++j) tmp[j] = f2bf(tile[kc + j][nl]);
    *reinterpret_cast<i32x4*>(dst + (size_t)(n0 + nl) * KK + k0 + kc) =
        *reinterpret_cast<i32x4*>(tmp);
  }
}

__global__ void init_state(ushort_t* __restrict__ hb, float* __restrict__ hf) {
  int i = blockIdx.x * 256 + threadIdx.x;   // grid 1024 -> 262144 threads
  if (i < NB * NH) { hb[i] = 0; hf[i] = 0.f; }
}

// ---------------------------------------------------------------------------
// Phase 1 (one timestep): [h|x_t](K=1536) @ B1t -> z (f32 ws), rh (bf16 ws)
// 256 blocks x 256 threads; block = (m-tile 32 rows) x (n-tile 64 of 2048).
// ---------------------------------------------------------------------------
__global__ void __launch_bounds__(256)
gru_phase1(const float* __restrict__ x, const ushort_t* __restrict__ B1t,
           const ushort_t* __restrict__ hb, ushort_t* __restrict__ rhb,
           const float* __restrict__ hf, float* __restrict__ zfb,
           const float* __restrict__ bz, const float* __restrict__ br, int t) {
  __shared__ __align__(16) char smem[24576];
  const int tid  = threadIdx.x;
  const int bid  = blockIdx.x;
  const int lane = tid & 63;
  const int w    = tid >> 6;
  const int wm   = w >> 1;
  const int wn   = w & 1;
  const int m0   = (bid >> 5) * 32;
  const int n1   = (bid & 31) * 64;
  const int l15  = lane & 15;
  const int l4   = lane >> 4;

  f32x4 acc0 = {0.f, 0.f, 0.f, 0.f}, acc1 = {0.f, 0.f, 0.f, 0.f};
  for (int kb = 0; kb < KK / BK; ++kb) {
    const int kbase = kb * BK;
    // stage A (32 x 128): [h | x_t]
#pragma unroll
    for (int i = 0; i < 2; ++i) {
      int c = tid + (i << 8);
      int r = c >> 4, kc = (c & 15) << 3;
      int m = m0 + r, k = kbase + kc;
      i32x4 v;
      if (k < NH) {
        v = *reinterpret_cast<const i32x4*>(hb + (size_t)m * NH + k);
      } else {
        const float* xp = x + (size_t)m * (NT * ND) + (size_t)t * ND + (k - NH);
        f32x4 f0 = *reinterpret_cast<const f32x4*>(xp);
        f32x4 f1 = *reinterpret_cast<const f32x4*>(xp + 4);
        v[0] = pack2(f0[0], f0[1]); v[1] = pack2(f0[2], f0[3]);
        v[2] = pack2(f1[0], f1[1]); v[3] = pack2(f1[2], f1[3]);
      }
      int off = (r << 8) + (((kc << 1)) ^ ((r & 7) << 4));
      *reinterpret_cast<i32x4*>(&smem[off]) = v;
    }
    // stage B (64 x 128) from B1t
#pragma unroll
    for (int i = 0; i < 4; ++i) {
      int c = tid + (i << 8);
      int n = c >> 4, kc = (c & 15) << 3;
      i32x4 v = *reinterpret_cast<const i32x4*>(B1t + (size_t)(n1 + n) * KK + kbase + kc);
      int off = 8192 + (n << 8) + (((kc << 1)) ^ ((n & 7) << 4));
      *reinterpret_cast<i32x4*>(&smem[off]) = v;
    }
    __syncthreads();
#pragma unroll
    for (int ks = 0; ks < 4; ++ks) {
      int kbyte = ks * 64 + l4 * 16;
      int ra = wm * 16 + l15;
      short8 a = *reinterpret_cast<short8*>(&smem[(ra << 8) + (kbyte ^ ((ra & 7) << 4))]);
      int nb0 = wn * 32 + l15;
      short8 b0 = *reinterpret_cast<short8*>(&smem[8192 + (nb0 << 8) + (kbyte ^ ((nb0 & 7) << 4))]);
      int nb1 = nb0 + 16;
      short8 b1 = *reinterpret_cast<short8*>(&smem[8192 + (nb1 << 8) + (kbyte ^ ((nb1 & 7) << 4))]);
      acc0 = __builtin_amdgcn_mfma_f32_16x16x32_bf16(a, b0, acc0, 0, 0, 0);
      acc1 = __builtin_amdgcn_mfma_f32_16x16x32_bf16(a, b1, acc1, 0, 0, 0);
    }
    __syncthreads();
  }
  // epilogue: sigmoid; z -> zfb (f32), rh -> rhb (bf16)
  int mrow = m0 + wm * 16 + l4 * 4;
#pragma unroll
  for (int f = 0; f < 2; ++f) {
    f32x4 av = f ? acc1 : acc0;
    int c = n1 + wn * 32 + f * 16 + l15;
#pragma unroll
    for (int j = 0; j < 4; ++j) {
      int m = mrow + j;
      float v = av[j];
      if (c < NH) {
        zfb[(size_t)m * NH + c] = sigmoidf_(v + bz[c]);
      } else {
        int cc = c - NH;
        float rv = sigmoidf_(v + br[cc]);
        rhb[(size_t)m * NH + cc] = f2bf(rv * hf[(size_t)m * NH + cc]);
      }
    }
  }
}

// ---------------------------------------------------------------------------
// Phase 2 (one timestep): [rh|x_t] @ B2t -> hc; h = (1-z)h + z*hc
// 256 blocks x 256 threads; block = (m-tile 32) x (n-tile 32 of 1024).
// ---------------------------------------------------------------------------
__global__ void __launch_bounds__(256)
gru_phase2(const float* __restrict__ x, const ushort_t* __restrict__ B2t,
           ushort_t* __restrict__ hb, const ushort_t* __restrict__ rhb,
           float* __restrict__ hf, const float* __restrict__ zfb,
           const float* __restrict__ bb, float* __restrict__ out, int t) {
  __shared__ __align__(16) char smem[16384];
  const int tid  = threadIdx.x;
  const int bid  = blockIdx.x;
  const int lane = tid & 63;
  const int w    = tid >> 6;
  const int wm   = w >> 1;
  const int wn   = w & 1;
  const int m0   = (bid >> 5) * 32;
  const int n2   = (bid & 31) * 32;
  const int l15  = lane & 15;
  const int l4   = lane >> 4;

  f32x4 acc = {0.f, 0.f, 0.f, 0.f};
  for (int kb = 0; kb < KK / BK; ++kb) {
    const int kbase = kb * BK;
    // stage A (32 x 128): [rh | x_t]
#pragma unroll
    for (int i = 0; i < 2; ++i) {
      int c = tid + (i << 8);
      int r = c >> 4, kc = (c & 15) << 3;
      int m = m0 + r, k = kbase + kc;
      i32x4 v;
      if (k < NH) {
        v = *reinterpret_cast<const i32x4*>(rhb + (size_t)m * NH + k);
      } else {
        const float* xp = x + (size_t)m * (NT * ND) + (size_t)t * ND + (k - NH);
        f32x4 f0 = *reinterpret_cast<const f32x4*>(xp);
        f32x4 f1 = *reinterpret_cast<const f32x4*>(xp + 4);
        v[0] = pack2(f0[0], f0[1]); v[1] = pack2(f0[2], f0[3]);
        v[2] = pack2(f1[0], f1[1]); v[3] = pack2(f1[2], f1[3]);
      }
      int off = (r << 8) + (((kc << 1)) ^ ((r & 7) << 4));
      *reinterpret_cast<i32x4*>(&smem[off]) = v;
    }
    // stage B (32 x 128) from B2t
#pragma unroll
    for (int i = 0; i < 2; ++i) {
      int c = tid + (i << 8);
      int n = c >> 4, kc = (c & 15) << 3;
      i32x4 v = *reinterpret_cast<const i32x4*>(B2t + (size_t)(n2 + n) * KK + kbase + kc);
      int off = 8192 + (n << 8) + (((kc << 1)) ^ ((n & 7) << 4));
      *reinterpret_cast<i32x4*>(&smem[off]) = v;
    }
    __syncthreads();
#pragma unroll
    for (int ks = 0; ks < 4; ++ks) {
      int kbyte = ks * 64 + l4 * 16;
      int ra = wm * 16 + l15;
      short8 a = *reinterpret_cast<short8*>(&smem[(ra << 8) + (kbyte ^ ((ra & 7) << 4))]);
      int nb = wn * 16 + l15;
      short8 b0 = *reinterpret_cast<short8*>(&smem[8192 + (nb << 8) + (kbyte ^ ((nb & 7) << 4))]);
      acc = __builtin_amdgcn_mfma_f32_16x16x32_bf16(a, b0, acc, 0, 0, 0);
    }
    __syncthreads();
  }
  // epilogue: tanh, gate update, publish h
  int mrow = m0 + wm * 16 + l4 * 4;
  int c = n2 + wn * 16 + l15;
#pragma unroll
  for (int j = 0; j < 4; ++j) {
    int m = mrow + j;
    size_t idx = (size_t)m * NH + c;
    float hc = tanhf_(acc[j] + bb[c]);
    float zv = zfb[idx];
    float hn = (1.f - zv) * hf[idx] + zv * hc;
    hf[idx] = hn;
    hb[idx] = f2bf(hn);
    if (t == NT - 1) out[idx] = hn;
  }
}

extern "C" void kernel_launch(void* const* d_in, const int* in_sizes, int n_in,
                              void* d_out, int out_size, void* d_ws, size_t ws_size,
                              hipStream_t stream) {
  const float* x  = (const float*)d_in[0];
  const float* W  = (const float*)d_in[1];
  const float* U  = (const float*)d_in[2];
  const float* Wz = (const float*)d_in[3];
  const float* Uz = (const float*)d_in[4];
  const float* Wr = (const float*)d_in[5];
  const float* Ur = (const float*)d_in[6];
  const float* bb = (const float*)d_in[7];
  const float* bz = (const float*)d_in[8];
  const float* br = (const float*)d_in[9];
  float* out = (float*)d_out;

  char* ws = (char*)d_ws;
  ushort_t* B1t = (ushort_t*)(ws);                  // 2048*1536*2 = 6291456
  ushort_t* B2t = (ushort_t*)(ws + 6291456);        // 1024*1536*2 = 3145728
  ushort_t* hb  = (ushort_t*)(ws + 9437184);        // 256*1024*2
  ushort_t* rhb = (ushort_t*)(ws + 9961472);        // 256*1024*2
  float*    hf  = (float*)   (ws + 10485760);       // 256*1024*4
  float*    zfb = (float*)   (ws + 11534336);       // 256*1024*4  (end 12582912)

  hipLaunchKernelGGL(repack_weights, dim3(24, 32, 2), dim3(256), 0, stream,
                     U, W, Uz, Wz, Ur, Wr, B1t, B2t);
  hipLaunchKernelGGL(init_state, dim3(1024), dim3(256), 0, stream, hb, hf);

  for (int t = 0; t < NT; ++t) {
    hipLaunchKernelGGL(gru_phase1, dim3(256), dim3(256), 0, stream,
                       x, B1t, hb, rhb, hf, zfb, bz, br, t);
    hipLaunchKernelGGL(gru_phase2, dim3(256), dim3(256), 0, stream,
                       x, B2t, hb, rhb, hf, zfb, bb, out, t);
  }
}